// Round 7
// baseline (483.459 us; speedup 1.0000x reference)
//
#include <hip/hip_runtime.h>

#define TAGS 64
#define SOS_IDX 1
#define EOS_IDX 2

typedef __attribute__((ext_vector_type(2))) float f2;

// quad_perm DPP: x1 = swap bit0 [1,0,3,2]; x2 = swap bit1 [2,3,0,1]
#define DPP_X1 0xB1
#define DPP_X2 0x4E
#define DPPF(v, ctrl) \
    __int_as_float(__builtin_amdgcn_mov_dpp(__float_as_int(v), (ctrl), 0xF, 0xF, true))

__device__ __forceinline__ float rl(float v, int l) {
    return __int_as_float(__builtin_amdgcn_readlane(__float_as_int(v), l));
}

// TWO batches per wave (A,B), lane i = 4g+c owns tag i for both.
// Per batch: x' = (E x) * s, s = exp(h_t)*rcp(z), z = x[3] via LDS broadcast,
// Ls += log2(z). The two chains are independent; B's FMA tree fills A's LDS
// round-trip stall and vice versa (the whole step is one unrolled basic block).
__global__ __launch_bounds__(64, 1) void crf_fwd_kernel(
    const float* __restrict__ h,
    const float* __restrict__ mask,
    const float* __restrict__ trans,
    float* __restrict__ out,
    int S, int B)
{
    const int bid = blockIdx.x;
    const int b0 = 2 * bid;
    const int b1v = 2 * bid + 1;
    const int b1 = (b1v < B) ? b1v : b0;    // safe dup if B odd
    const int lane = threadIdx.x;
    const int g = lane >> 2;
    const int c = lane & 3;

    __shared__ __align__(16) float u_sh[2][TAGS];

    // E fragment (shared by both batches): slot k = exp(trans[4g+(c^k)][16c..16c+16))
    f2 ew2[4][8];
    #pragma unroll
    for (int k = 0; k < 4; ++k) {
        const int row = 4 * g + (c ^ k);
        const float4* tr = reinterpret_cast<const float4*>(trans + row * TAGS + 16 * c);
        #pragma unroll
        for (int q = 0; q < 4; ++q) {
            float4 v = tr[q];
            f2 lo, hi;
            lo.x = __expf(v.x); lo.y = __expf(v.y);   // exp(-10000) -> 0 exact
            hi.x = __expf(v.z); hi.y = __expf(v.w);
            ew2[k][2*q]   = lo;
            ew2[k][2*q+1] = hi;
        }
    }

    const float* hbA = h + (size_t)b0 * (size_t)S * TAGS + lane;
    const float* hbB = h + (size_t)b1 * (size_t)S * TAGS + lane;
    const float* mbA = mask + (size_t)b0 * (size_t)S;
    const float* mbB = mask + (size_t)b1 * (size_t)S;

    float xA = (lane == SOS_IDX) ? 1.0f : 0.0f;
    float xB = xA;
    float LsA = 0.0f, LsB = 0.0f;

    float hbufA[8], hbufB[8];
    #pragma unroll
    for (int q = 0; q < 8; ++q) {
        int t = (q < S) ? q : (S - 1);
        hbufA[q] = hbA[(size_t)t * TAGS];
        hbufB[q] = hbB[(size_t)t * TAGS];
    }

    const int NC = S >> 6;                  // S % 64 == 0 (S = 1024)
    float mregA = mbA[lane];
    float mregB = mbB[lane];

    const float4* uA4 = reinterpret_cast<const float4*>(u_sh[0]);
    const float4* uB4 = reinterpret_cast<const float4*>(u_sh[1]);

    for (int ch = 0; ch < NC; ++ch) {
        const int cn = (ch + 1 < NC) ? (ch + 1) : ch;
        float mnA = mbA[(size_t)cn * 64 + lane];
        float mnB = mbB[(size_t)cn * 64 + lane];

        for (int t0 = 0; t0 < 64; t0 += 8) {
            float ehqA[8], ehqB[8];
            #pragma unroll
            for (int q = 0; q < 8; ++q) { ehqA[q] = __expf(hbufA[q]); ehqB[q] = __expf(hbufB[q]); }
            const int base = ch * 64 + t0 + 8;
            #pragma unroll
            for (int q = 0; q < 8; ++q) {
                int tn = base + q;
                if (tn > S - 1) tn = S - 1;
                hbufA[q] = hbA[(size_t)tn * TAGS];
                hbufB[q] = hbB[(size_t)tn * TAGS];
            }

            #pragma unroll
            for (int q = 0; q < 8; ++q) {
                // --- chain heads: publish both states, start all reads ---
                u_sh[0][lane] = xA;
                u_sh[1][lane] = xB;
                const float zrA = u_sh[0][3];       // b32 broadcast, arrives first
                const float zrB = u_sh[1][3];
                float4 ca0 = uA4[(c << 2) + 0];
                float4 ca1 = uA4[(c << 2) + 1];
                float4 ca2 = uA4[(c << 2) + 2];
                float4 ca3 = uA4[(c << 2) + 3];
                float4 cb0 = uB4[(c << 2) + 0];
                float4 cb1 = uB4[(c << 2) + 1];
                float4 cb2 = uB4[(c << 2) + 2];
                float4 cb3 = uB4[(c << 2) + 3];
                __builtin_amdgcn_wave_barrier();    // pin stores+reads above the rest

                // --- off-chain scalars (fill the wait window) ---
                const float mA = rl(mregA, t0 + q);
                const float mB = rl(mregB, t0 + q);
                const float zA = (zrA > 0.0f) ? zrA : 1.0f;
                const float zB = (zrB > 0.0f) ? zrB : 1.0f;
                const float sA = ehqA[q] * __builtin_amdgcn_rcpf(zA);
                const float sB = ehqB[q] * __builtin_amdgcn_rcpf(zB);
                const float lgA = __log2f(zA);
                const float lgB = __log2f(zB);

                f2 uuA[8], uuB[8];
                uuA[0].x = ca0.x; uuA[0].y = ca0.y;  uuA[1].x = ca0.z; uuA[1].y = ca0.w;
                uuA[2].x = ca1.x; uuA[2].y = ca1.y;  uuA[3].x = ca1.z; uuA[3].y = ca1.w;
                uuA[4].x = ca2.x; uuA[4].y = ca2.y;  uuA[5].x = ca2.z; uuA[5].y = ca2.w;
                uuA[6].x = ca3.x; uuA[6].y = ca3.y;  uuA[7].x = ca3.z; uuA[7].y = ca3.w;
                uuB[0].x = cb0.x; uuB[0].y = cb0.y;  uuB[1].x = cb0.z; uuB[1].y = cb0.w;
                uuB[2].x = cb1.x; uuB[2].y = cb1.y;  uuB[3].x = cb1.z; uuB[3].y = cb1.w;
                uuB[4].x = cb2.x; uuB[4].y = cb2.y;  uuB[5].x = cb2.z; uuB[5].y = cb2.w;
                uuB[6].x = cb3.x; uuB[6].y = cb3.y;  uuB[7].x = cb3.z; uuB[7].y = cb3.w;

                float ppA[4], ppB[4];
                #pragma unroll
                for (int k = 0; k < 4; ++k) {
                    f2 aA = ew2[k][0] * uuA[0];
                    f2 bA = ew2[k][1] * uuA[1];
                    f2 aB = ew2[k][0] * uuB[0];
                    f2 bB = ew2[k][1] * uuB[1];
                    aA = __builtin_elementwise_fma(ew2[k][2], uuA[2], aA);
                    bA = __builtin_elementwise_fma(ew2[k][3], uuA[3], bA);
                    aB = __builtin_elementwise_fma(ew2[k][2], uuB[2], aB);
                    bB = __builtin_elementwise_fma(ew2[k][3], uuB[3], bB);
                    aA = __builtin_elementwise_fma(ew2[k][4], uuA[4], aA);
                    bA = __builtin_elementwise_fma(ew2[k][5], uuA[5], bA);
                    aB = __builtin_elementwise_fma(ew2[k][4], uuB[4], aB);
                    bB = __builtin_elementwise_fma(ew2[k][5], uuB[5], bB);
                    aA = __builtin_elementwise_fma(ew2[k][6], uuA[6], aA);
                    bA = __builtin_elementwise_fma(ew2[k][7], uuA[7], bA);
                    aB = __builtin_elementwise_fma(ew2[k][6], uuB[6], aB);
                    bB = __builtin_elementwise_fma(ew2[k][7], uuB[7], bB);
                    aA = aA + bA;
                    aB = aB + bB;
                    ppA[k] = aA.x + aA.y;
                    ppB[k] = aB.x + aB.y;
                }

                // rotated quad reduce-scatter per batch
                ppA[0] += DPPF(ppA[1], DPP_X1);
                ppB[0] += DPPF(ppB[1], DPP_X1);
                ppA[2] += DPPF(ppA[3], DPP_X1);
                ppB[2] += DPPF(ppB[3], DPP_X1);
                ppA[0] += DPPF(ppA[2], DPP_X2);
                ppB[0] += DPPF(ppB[2], DPP_X2);

                const float xnA = ppA[0] * sA;
                const float xnB = ppB[0] * sB;
                const bool mmA = (mA != 0.0f);
                const bool mmB = (mB != 0.0f);
                xA  = mmA ? xnA : xA;
                LsA = mmA ? (LsA + lgA) : LsA;
                xB  = mmB ? xnB : xB;
                LsB = mmB ? (LsB + lgB) : LsB;
                __builtin_amdgcn_wave_barrier();
            }
        }
        mregA = mnA;
        mregB = mnB;
    }

    // out[b] = ln2*Ls + log(sum_i x[i] * exp(trans[EOS, i]))
    const float et = __expf(trans[EOS_IDX * TAGS + lane]);
    float vA = xA * et;
    float vB = xB * et;
    #pragma unroll
    for (int off = 32; off > 0; off >>= 1) {
        vA += __shfl_xor(vA, off, 64);
        vB += __shfl_xor(vB, off, 64);
    }
    if (lane == 0) {
        out[b0] = 0.69314718055994531f * LsA + __logf(vA);
        if (b1v < B) out[b1v] = 0.69314718055994531f * LsB + __logf(vB);
    }
}

extern "C" void kernel_launch(void* const* d_in, const int* in_sizes, int n_in,
                              void* d_out, int out_size, void* d_ws, size_t ws_size,
                              hipStream_t stream) {
    const float* h     = (const float*)d_in[0];
    const float* mask  = (const float*)d_in[1];
    const float* trans = (const float*)d_in[2];
    float* out = (float*)d_out;

    const int B = out_size;                 // 512
    const int S = in_sizes[1] / B;          // 1024  (mask is B*S)

    crf_fwd_kernel<<<(B + 1) / 2, 64, 0, stream>>>(h, mask, trans, out, S, B);
}